// Round 1
// baseline (75.696 us; speedup 1.0000x reference)
//
#include <hip/hip_runtime.h>

// PTS loss: B=32, N=2048.
//   non-sym batch: sum_n ||R_e p_n - R_g p_n||^2
//   sym batch:     sum_n min_m ||R_e p_n - R_g p_m||^2
// out = (sum_s + sum_p) / (2*N*B), single f32 scalar.
//
// R6: occupancy/latency round.
//  - A: TPB 256->512 (PX 4/thread). Sym blocks become 8 waves -> 2 waves/SIMD,
//    giving TLP to hide ds_read_b128 + fmin-chain latency (was 1 wave/SIMD).
//  - B: grid 32 -> (32 x 8) blocks, one x-point per thread (16 independent
//    strided loads instead of a 128-load serial chain in 32 blocks).
// Structure otherwise = R5 two-kernel (R4 fused single-kernel regressed 56us
// from device-scope fences; do not refuse without grid-sync evidence).

#define NPTS  2048
#define MS    16            // m-chunks per sym batch
#define MCH   (NPTS / MS)   // 128 candidates per chunk
#define TPB_A 512
#define PXA   (NPTS / TPB_A) // 4 x-points per thread
#define TPB_B 256
#define NSB   8             // n-chunk blocks per batch in kernel B
#define NCHB  (NPTS / NSB)  // 256 points per B-block (1 per thread)

__device__ __forceinline__ void quat2mat(const float* __restrict__ q, float R[9]) {
    float w = q[0], x = q[1], y = q[2], z = q[3];
    float inv = 1.0f / sqrtf(w*w + x*x + y*y + z*z);
    w *= inv; x *= inv; y *= inv; z *= inv;
    R[0] = 1.f - 2.f*(y*y + z*z); R[1] = 2.f*(x*y - w*z);       R[2] = 2.f*(x*z + w*y);
    R[3] = 2.f*(x*y + w*z);       R[4] = 1.f - 2.f*(x*x + z*z); R[5] = 2.f*(y*z - w*x);
    R[6] = 2.f*(x*z - w*y);       R[7] = 2.f*(y*z + w*x);       R[8] = 1.f - 2.f*(x*x + y*y);
}

template <int NW>
__device__ __forceinline__ float block_reduce_add(float v, float* red) {
    #pragma unroll
    for (int off = 32; off > 0; off >>= 1)
        v += __shfl_down(v, off, 64);
    const int tid = threadIdx.x;
    if ((tid & 63) == 0) red[tid >> 6] = v;
    __syncthreads();
    float s = 0.f;
    #pragma unroll
    for (int w = 0; w < NW; ++w) s += red[w];
    return s;
}

__global__ __launch_bounds__(TPB_A) void pts_loss_A(
    const float* __restrict__ q_est, const float* __restrict__ q_gt,
    const float* __restrict__ pts, const int* __restrict__ symmetries,
    float* __restrict__ out, float* __restrict__ partial,
    float* __restrict__ bsum)
{
    const int b   = blockIdx.x;
    const int ms  = blockIdx.y;
    const int tid = threadIdx.x;

    __shared__ float4 ybuf[MCH];          // 2 KB
    __shared__ float  red[TPB_A / 64];

    // zero the scalar output: single producer, reads happen after the
    // kernel-boundary (kernel B), so no fence needed.
    if (b == 0 && ms == 0 && tid == 0) *out = 0.f;

    const bool is_sym = symmetries[b] != 0;   // block-uniform
    const float* pb = pts + (size_t)b * NPTS * 3;

    if (!is_sym) {
        if (ms != 0) return;
        float Re[9], Rg[9];
        quat2mat(q_est + 4*b, Re);
        quat2mat(q_gt  + 4*b, Rg);
        float s = 0.f;
        #pragma unroll
        for (int k = 0; k < PXA; ++k) {
            int n = k * TPB_A + tid;
            float p0 = pb[3*n+0], p1 = pb[3*n+1], p2 = pb[3*n+2];
            float d0 = (Re[0]-Rg[0])*p0 + (Re[1]-Rg[1])*p1 + (Re[2]-Rg[2])*p2;
            float d1 = (Re[3]-Rg[3])*p0 + (Re[4]-Rg[4])*p1 + (Re[5]-Rg[5])*p2;
            float d2 = (Re[6]-Rg[6])*p0 + (Re[7]-Rg[7])*p1 + (Re[8]-Rg[8])*p2;
            s += d0*d0 + d1*d1 + d2*d2;
        }
        s = block_reduce_add<TPB_A/64>(s, red);
        if (tid == 0) bsum[b] = s;
        return;
    }

    float Re[9], Rg[9];
    quat2mat(q_est + 4*b, Re);
    quat2mat(q_gt  + 4*b, Rg);

    // stage this block's y-chunk: candidate m = ms*MCH + tid  (tid < MCH)
    if (tid < MCH) {
        int m = ms * MCH + tid;
        float p0 = pb[3*m+0], p1 = pb[3*m+1], p2 = pb[3*m+2];
        float y0 = Rg[0]*p0 + Rg[1]*p1 + Rg[2]*p2;
        float y1 = Rg[3]*p0 + Rg[4]*p1 + Rg[5]*p2;
        float y2 = Rg[6]*p0 + Rg[7]*p1 + Rg[8]*p2;
        ybuf[tid] = make_float4(y0, y1, y2, y0*y0 + y1*y1 + y2*y2);
    }
    __syncthreads();

    // my PXA x-points: n = k*TPB_A + tid (coalesced)
    float nx0[PXA], nx1[PXA], nx2[PXA], xx[PXA], mins[PXA];
    #pragma unroll
    for (int k = 0; k < PXA; ++k) {
        int n = k * TPB_A + tid;
        float p0 = pb[3*n+0], p1 = pb[3*n+1], p2 = pb[3*n+2];
        float x0 = Re[0]*p0 + Re[1]*p1 + Re[2]*p2;
        float x1 = Re[3]*p0 + Re[4]*p1 + Re[5]*p2;
        float x2 = Re[6]*p0 + Re[7]*p1 + Re[8]*p2;
        nx0[k] = -2.f*x0; nx1[k] = -2.f*x1; nx2[k] = -2.f*x2;
        xx[k]  = x0*x0 + x1*x1 + x2*x2;
        mins[k] = 1e30f;
    }

    // min over this chunk: one broadcast b128 read feeds 4 points (16 VALU)
    #pragma unroll 8
    for (int m = 0; m < MCH; ++m) {
        float4 y = ybuf[m];
        #pragma unroll
        for (int k = 0; k < PXA; ++k) {
            float t = fmaf(nx0[k], y.x, fmaf(nx1[k], y.y, fmaf(nx2[k], y.z, y.w)));
            mins[k] = fminf(mins[k], t);
        }
    }

    // publish chunk partial with xx folded in
    float* pp = partial + ((size_t)b * MS + ms) * NPTS;
    #pragma unroll
    for (int k = 0; k < PXA; ++k)
        pp[k * TPB_A + tid] = mins[k] + xx[k];
}

__global__ __launch_bounds__(TPB_B) void pts_loss_B(
    const int* __restrict__ symmetries,
    const float* __restrict__ partial,
    const float* __restrict__ bsum, float* __restrict__ out, float scale)
{
    const int b   = blockIdx.x;
    const int bs  = blockIdx.y;
    const int tid = threadIdx.x;
    __shared__ float red[TPB_B / 64];

    if (symmetries[b] == 0) {
        if (bs == 0 && tid == 0) atomicAdd(out, bsum[b] * scale);
        return;
    }

    // one x-point per thread; 16 independent strided loads, then min
    const int n = bs * NCHB + tid;
    const float* pb = partial + (size_t)b * MS * NPTS;
    float v = pb[n];
    #pragma unroll
    for (int ms = 1; ms < MS; ++ms)
        v = fminf(v, pb[ms * NPTS + n]);

    float s = block_reduce_add<TPB_B/64>(v, red);
    if (tid == 0) atomicAdd(out, s * scale);
}

extern "C" void kernel_launch(void* const* d_in, const int* in_sizes, int n_in,
                              void* d_out, int out_size, void* d_ws, size_t ws_size,
                              hipStream_t stream) {
    const float* q_est = (const float*)d_in[0];
    const float* q_gt  = (const float*)d_in[1];
    // d_in[2] = T, unused by the reference
    const float* pts   = (const float*)d_in[3];
    const int*   sym   = (const int*)d_in[4];
    float* out = (float*)d_out;

    const int B = in_sizes[0] / 4;  // 32
    const float scale = 1.0f / (2.0f * (float)NPTS * (float)B);

    float* partial = (float*)d_ws;                       // B*MS*NPTS = 4 MB
    float* bsum    = partial + (size_t)B * MS * NPTS;    // B floats

    dim3 gridA(B, MS);
    pts_loss_A<<<gridA, TPB_A, 0, stream>>>(q_est, q_gt, pts, sym, out, partial, bsum);
    dim3 gridB(B, NSB);
    pts_loss_B<<<gridB, TPB_B, 0, stream>>>(sym, partial, bsum, out, scale);
}